// Round 13
// baseline (42.984 us; speedup 1.0000x reference)
//
#include <hip/hip_runtime.h>

#define CCH  85
#define N0   (16*13*13*3)   // 8112
#define N1   (16*26*26*3)   // 32448
#define N2   (16*52*52*3)   // 129792
#define NTOT (N0+N1+N2)     // 170352
#define NBLK ((NTOT + 255) / 256)   // 666
#define BPB  40   // max boxes per K1 block (block spans <=2 images, <=20 each)
#define MAXB 32   // max boxes per (layer,image)

// d_ws layout (bytes):
//   RECBOX_OFF = 0       : float4[NTOT]  (pl,pr,pt,pb)     per cell
//   RECMETA_OFF= 2725632 : float2[NTOT]  (p_area, clneg)   per cell
//   CNT_OFF    = 4088448 : int[NBLK]     per-K1-block private box count
//   TAGS_OFF   = 4091136 : int[NBLK*BPB] lb tag per private box
//   BOX_OFF    = 4197696 : float4[NBLK*BPB] private boxes
#define RECBOX_OFF  0
#define RECMETA_OFF 2725632
#define CNT_OFF     4088448
#define TAGS_OFF    4091136
#define BOX_OFF     4197696

typedef float v4f __attribute__((ext_vector_type(4), aligned(4)));

__device__ __forceinline__ void decode(int i, int& l, int& li, int& g) {
    if (i < N0)           { l = 0; li = i;           g = 13; }
    else if (i < N0 + N1) { l = 1; li = i - N0;      g = 26; }
    else                  { l = 2; li = i - N0 - N1; g = 52; }
}

// anchors fixed by reference setup_inputs; l0->mask[6,7,8], l1->[3,4,5], l2->[0,1,2]
__device__ __forceinline__ float anc_x(int l, int a) {
    if (l == 0) return (a == 0) ? 116.f : (a == 1) ? 156.f : 373.f;
    if (l == 1) return (a == 0) ?  30.f : (a == 1) ?  62.f :  59.f;
    return          (a == 0) ?  10.f : (a == 1) ?  16.f :  33.f;
}
__device__ __forceinline__ float anc_y(int l, int a) {
    if (l == 0) return (a == 0) ?  90.f : (a == 1) ? 198.f : 326.f;
    if (l == 1) return (a == 0) ?  61.f : (a == 1) ?  45.f : 119.f;
    return          (a == 0) ?  13.f : (a == 1) ?  30.f :  23.f;
}

__device__ __forceinline__ int lb_of(int gi) {
    int ll, lli, gg;
    decode(gi, ll, lli, gg);
    return ll * 16 + lli / (gg * gg * 3);
}

// ---------------------------------------------------------------------------
// K1: ALL scattered traffic in one latency shadow (pred[0:5] + tgt[4] issued
// together). Computes: conf-pos + full obj-row loss (ballot-inline, waves
// cooperate) -> atomicAdd; per-cell precomputed records (pred box, p_area,
// clneg=-log(1-pc)) -> contiguous arrays for K2; private box lists.
// Ref's top_k(32)+(vals>0) mask == set of obj>0 boxes (<=20/image < 32);
// set-max IoU is order-independent -> collection order irrelevant.
// ---------------------------------------------------------------------------
__global__ void __launch_bounds__(256) k1_gather(
        const float* __restrict__ p0, const float* __restrict__ t0,
        const float* __restrict__ p1, const float* __restrict__ t1,
        const float* __restrict__ p2, const float* __restrict__ t2,
        float4* __restrict__ recbox, float2* __restrict__ recmeta,
        int* __restrict__ counts_priv, int* __restrict__ tags_priv,
        float4* __restrict__ boxes_priv, float* __restrict__ out) {
    int bid = blockIdx.x;
    int tid = threadIdx.x;
    int i = bid * 256 + tid;
    bool valid = i < NTOT;

    int l = 0, li = 0, g = 13;
    if (valid) decode(i, l, li, g);
    const float* P = (l == 0) ? p0 : (l == 1) ? p1 : p2;
    const float* T = (l == 0) ? t0 : (l == 1) ? t1 : t2;
    size_t base = (size_t)li * CCH;

    // ONE latency shadow: pred ch0..4 + tgt obj issued back-to-back
    v4f pv4 = {0.5f, 0.5f, 0.0f, 0.0f};
    float pc = 0.5f, obj = 0.0f;
    if (valid) {
        pv4 = *(const v4f*)(P + base);
        pc  = P[base + 4];
        obj = T[base + 4];
    }

    int cpi = g * g * 3;
    int b = li / cpi;
    int c = li % cpi;
    int a = c % 3;
    int w = (c / 3) % g;
    int h = c / (3 * g);
    int lb = l * 16 + b;

    bool isobj = valid && obj > 0.0f;

    // private box-list collect (block-owned slots -> no zeroing needed)
    __shared__ int cnt;
    __shared__ float4 lbox[BPB];
    __shared__ int llb[BPB];
    if (tid == 0) cnt = 0;
    __syncthreads();
    if (isobj) {
        int pos = atomicAdd(&cnt, 1);
        if (pos < BPB) {
            v4f tb4 = *(const v4f*)(T + base);
            lbox[pos] = make_float4(tb4.x, tb4.y, tb4.z, tb4.w);
            llb[pos]  = lb;
        }
    }
    __syncthreads();
    int n = cnt < BPB ? cnt : BPB;
    if (tid == 0) counts_priv[bid] = n;
    if (tid < n) {
        boxes_priv[bid * BPB + tid] = lbox[tid];
        tags_priv[bid * BPB + tid]  = llb[tid];
    }

    // per-cell record for K2 (zeros for obj/invalid cells: iou=0, clneg=0)
    float4 rbox = make_float4(0.f, 0.f, 0.f, 0.f);
    float2 rmeta = make_float2(0.f, 0.f);
    if (valid && !isobj) {
        float ax = anc_x(l, a), ay = anc_y(l, a);
        float gf = (float)g;
        float pxn = (pv4.x + (float)w) / gf;
        float pyn = (pv4.y + (float)h) / gf;
        float pwn = __expf(pv4.z) * ax * (1.0f / 416.0f);
        float phn = __expf(pv4.w) * ay * (1.0f / 416.0f);
        rbox = make_float4(pxn - pwn * 0.5f, pxn + pwn * 0.5f,
                           pyn - phn * 0.5f, pyn + phn * 0.5f);
        rmeta = make_float2(pwn * phn, -__logf(1.0f - pc));
    }
    if (valid) {
        recbox[i]  = rbox;
        recmeta[i] = rmeta;
    }

    // conf-pos + obj-row full loss, ballot-inline (wave cooperates per row)
    float acc = 0.0f;
    int lane = tid & 63, wid = tid >> 6;
    if (isobj) acc = -__logf(pc);                    // (obj+(1-obj)*ignore)==1

    unsigned long long mask = __ballot(isobj);
    while (mask) {
        int src = __ffsll(mask) - 1;
        mask &= mask - 1;
        int l2  = __shfl(l,  src, 64);
        int li2 = __shfl(li, src, 64);
        const float *P2 = (l2 == 0) ? p0 : (l2 == 1) ? p1 : p2;
        const float *T2 = (l2 == 0) ? t0 : (l2 == 1) ? t1 : t2;
        int g2 = (l2 == 0) ? 13 : (l2 == 1) ? 26 : 52;
        int cpi2 = g2 * g2 * 3;
        int c2 = li2 % cpi2;
        int a2 = c2 % 3;
        int w2 = (c2 / 3) % g2;
        int h2 = c2 / (3 * g2);
        size_t base2 = (size_t)li2 * CCH;

        float pv = P2[base2 + lane];
        float tv = T2[base2 + lane];
        bool has2 = lane < (CCH - 64);               // lanes 0..20 -> ch 64..84
        float pvB = 1.0f, tvB = 1.0f;
        if (has2) { pvB = P2[base2 + 64 + lane]; tvB = T2[base2 + 64 + lane]; }

        float tx = __shfl(tv, 0, 64), ty = __shfl(tv, 1, 64);
        float tw = __shfl(tv, 2, 64), th = __shfl(tv, 3, 64);
        float qx = __shfl(pv, 0, 64), qy = __shfl(pv, 1, 64);
        float qw = __shfl(pv, 2, 64), qh = __shfl(pv, 3, 64);

        if (lane >= 5)   // cls ch 5..63
            acc += -(tv * __logf(pv) + (1.0f - tv) * __logf(1.0f - pv));
        if (has2)        // cls ch 64..84
            acc += -(tvB * __logf(pvB) + (1.0f - tvB) * __logf(1.0f - pvB));

        if (lane == 0) {
            float scale = 2.0f - tw * th;
            float gf = (float)g2;
            float rtx = tx * gf - (float)w2;
            float rty = ty * gf - (float)h2;
            float ax = anc_x(l2, a2), ay = anc_y(l2, a2);
            float rtw = __logf(tw * 416.0f / ax);    // tw,th > 0 at obj cells
            float rth = __logf(th * 416.0f / ay);
            acc += (-(rtx * __logf(qx) + (1.0f - rtx) * __logf(1.0f - qx))) * scale;
            acc += (-(rty * __logf(qy) + (1.0f - rty) * __logf(1.0f - qy))) * scale;
            acc += 0.5f * (qw - rtw) * (qw - rtw) * scale;
            acc += 0.5f * (qh - rth) * (qh - rth) * scale;
        }
    }

    acc *= (1.0f / 16.0f);   // mean over batch == sum/16
    for (int off = 32; off > 0; off >>= 1)
        acc += __shfl_down(acc, off, 64);
    __shared__ float s[4];
    if (lane == 0) s[wid] = acc;
    __syncthreads();
    if (tid == 0)
        atomicAdd(out, s[0] + s[1] + s[2] + s[3]);
}

// ---------------------------------------------------------------------------
// K2: PURE STREAMING. Read per-cell records coalesced, rebuild span box lists
// from private lists (<=33 parallel threads), 20-iter IoU vs LDS, add clneg
// where maxiou < 0.5. No pred/tgt access at all.
// ---------------------------------------------------------------------------
__global__ void __launch_bounds__(256) k2_ignore(
        const float4* __restrict__ recbox, const float2* __restrict__ recmeta,
        const int* __restrict__ counts_priv, const int* __restrict__ tags_priv,
        const float4* __restrict__ boxes_priv, float* __restrict__ out) {
    int bid = blockIdx.x;
    int tid = threadIdx.x;
    int i = bid * 256 + tid;
    bool valid = i < NTOT;

    float4 rbox = make_float4(0.f, 0.f, 0.f, 0.f);
    float2 rmeta = make_float2(0.f, 0.f);
    if (valid) { rbox = recbox[i]; rmeta = recmeta[i]; }

    int lb = valid ? lb_of(i) : 0;
    int iLast = (bid * 256 + 255 < NTOT) ? bid * 256 + 255 : NTOT - 1;
    int lbA = lb_of(bid * 256);
    int lbB = lb_of(iLast);

    __shared__ float4 sbox[2][MAXB];
    __shared__ int scnt[2];
    if (tid < 2) scnt[tid] = 0;
    __syncthreads();

    auto gather = [&](int lbT, int listIdx, int tbase) {
        int lT = lbT >> 4, bT = lbT & 15;
        int Ls, cpiT;
        if (lT == 0)      { Ls = 0;       cpiT = 13 * 13 * 3; }
        else if (lT == 1) { Ls = N0;      cpiT = 26 * 26 * 3; }
        else              { Ls = N0 + N1; cpiT = 52 * 52 * 3; }
        int jstart = (Ls + bT * cpiT) >> 8;
        int jend   = (Ls + (bT + 1) * cpiT - 1) >> 8;
        int t = tid - tbase;
        if (t >= 0 && t <= jend - jstart) {
            int j = jstart + t;
            int cj = counts_priv[j];
            if (cj > BPB) cj = BPB;
            for (int k = 0; k < cj; ++k) {
                if (tags_priv[j * BPB + k] == lbT) {
                    int p = atomicAdd(&scnt[listIdx], 1);
                    if (p < MAXB) sbox[listIdx][p] = boxes_priv[j * BPB + k];
                }
            }
        }
    };
    gather(lbA, 0, 0);
    if (lbB != lbA) gather(lbB, 1, 128);
    __syncthreads();

    float acc = 0.0f;
    if (valid) {
        int listIdx = (lb == lbA) ? 0 : 1;
        int cntL = scnt[listIdx];
        if (cntL > MAXB) cntL = MAXB;
        const float4* bx = sbox[listIdx];
        float pl = rbox.x, pr = rbox.y, pt = rbox.z, pb = rbox.w;
        float p_area = rmeta.x;
        float maxiou = 0.0f;
        #pragma unroll 4
        for (int k = 0; k < cntL; ++k) {
            float4 tb = bx[k];
            float il = fmaxf(pl, tb.x - tb.z * 0.5f);
            float ir = fminf(pr, tb.x + tb.z * 0.5f);
            float it = fmaxf(pt, tb.y - tb.w * 0.5f);
            float ib = fminf(pb, tb.y + tb.w * 0.5f);
            float iw = fmaxf(ir - il, 0.0f);
            float ih = fmaxf(ib - it, 0.0f);
            float inter = iw * ih;
            float iou = __fdividef(inter, p_area + tb.z * tb.w - inter);
            maxiou = fmaxf(maxiou, iou);
        }
        if (maxiou < 0.5f) acc = rmeta.y;   // clneg (0 for obj/zero cells)
    }

    acc *= (1.0f / 16.0f);
    for (int off = 32; off > 0; off >>= 1)
        acc += __shfl_down(acc, off, 64);
    __shared__ float s[4];
    int lane = tid & 63, wid = tid >> 6;
    if (lane == 0) s[wid] = acc;
    __syncthreads();
    if (tid == 0)
        atomicAdd(out, s[0] + s[1] + s[2] + s[3]);
}

extern "C" void kernel_launch(void* const* d_in, const int* in_sizes, int n_in,
                              void* d_out, int out_size, void* d_ws, size_t ws_size,
                              hipStream_t stream) {
    const float* p0 = (const float*)d_in[0];
    const float* t0 = (const float*)d_in[1];
    const float* p1 = (const float*)d_in[2];
    const float* t1 = (const float*)d_in[3];
    const float* p2 = (const float*)d_in[4];
    const float* t2 = (const float*)d_in[5];

    float4* recbox      = (float4*)((char*)d_ws + RECBOX_OFF);
    float2* recmeta     = (float2*)((char*)d_ws + RECMETA_OFF);
    int*    counts_priv = (int*)((char*)d_ws + CNT_OFF);
    int*    tags_priv   = (int*)((char*)d_ws + TAGS_OFF);
    float4* boxes_priv  = (float4*)((char*)d_ws + BOX_OFF);
    float*  outp        = (float*)d_out;

    (void)hipMemsetAsync(d_out, 0, sizeof(float), stream);

    k1_gather<<<NBLK, 256, 0, stream>>>(p0, t0, p1, t1, p2, t2,
                                        recbox, recmeta,
                                        counts_priv, tags_priv, boxes_priv, outp);
    k2_ignore<<<NBLK, 256, 0, stream>>>(recbox, recmeta,
                                        counts_priv, tags_priv, boxes_priv, outp);
}

// Round 14
// 40.699 us; speedup vs baseline: 1.0561x; 1.0561x over previous
//
#include <hip/hip_runtime.h>

#define CCH  85
#define MAXB 32

typedef float v4f __attribute__((ext_vector_type(4), aligned(4)));

// anchors fixed by reference setup_inputs; l0->mask[6,7,8], l1->[3,4,5], l2->[0,1,2]
__device__ __forceinline__ float anc_x(int l, int a) {
    if (l == 0) return (a == 0) ? 116.f : (a == 1) ? 156.f : 373.f;
    if (l == 1) return (a == 0) ?  30.f : (a == 1) ?  62.f :  59.f;
    return          (a == 0) ?  10.f : (a == 1) ?  16.f :  33.f;
}
__device__ __forceinline__ float anc_y(int l, int a) {
    if (l == 0) return (a == 0) ?  90.f : (a == 1) ? 198.f : 326.f;
    if (l == 1) return (a == 0) ?  61.f : (a == 1) ?  45.f : 119.f;
    return          (a == 0) ?  13.f : (a == 1) ?  30.f :  23.f;
}

// ---------------------------------------------------------------------------
// ONE kernel, XCD-pinned spans, zero cross-block communication.
// class = blockIdx.x & 7 (= XCD on MI355X: consecutive blockIdx round-robin
// XCDs). Each class owns 6 spans: l2 images {c, c+8} (32 chunks each, FIRST
// in dispatch order), l1 {c, c+8} (8 chunks), l0 {c, c+8} (2 chunks) = 84
// chunk-slots -> grid 672. Every block re-scans its span's obj channel; all
// same-span blocks share ONE XCD L2, so HBM fetches the span's obj sectors
// once (this was R9's 8x overfetch; the swizzle is the fix).
// Ref's top_k(32)+(vals>0) mask == set of obj>0 boxes (<=20/image < 32);
// set-max IoU is order-independent -> append order irrelevant.
// ---------------------------------------------------------------------------
__global__ void __launch_bounds__(256) yolo_swz(
        const float* __restrict__ p0, const float* __restrict__ t0,
        const float* __restrict__ p1, const float* __restrict__ t1,
        const float* __restrict__ p2, const float* __restrict__ t2,
        float* __restrict__ out) {
    int bid = blockIdx.x;
    int tid = threadIdx.x;
    int cls = bid & 7;        // XCD class
    int idx = bid >> 3;       // 0..83 slot within class

    int l, b, chunk;
    if (idx < 32)      { l = 2; b = cls;     chunk = idx; }
    else if (idx < 64) { l = 2; b = cls + 8; chunk = idx - 32; }
    else if (idx < 72) { l = 1; b = cls;     chunk = idx - 64; }
    else if (idx < 80) { l = 1; b = cls + 8; chunk = idx - 72; }
    else if (idx < 82) { l = 0; b = cls;     chunk = idx - 80; }
    else               { l = 0; b = cls + 8; chunk = idx - 82; }

    int g   = (l == 0) ? 13 : (l == 1) ? 26 : 52;
    int cpi = g * g * 3;                       // 507 / 2028 / 8112
    const float* P = (l == 0) ? p0 : (l == 1) ? p1 : p2;
    const float* T = (l == 0) ? t0 : (l == 1) ? t1 : t2;
    size_t sbase = (size_t)b * cpi * CCH;

    int mycell = chunk * 256 + tid;
    bool valid = mycell < cpi;

    // (1) own-cell pred gather first (HBM latency shadow under the scan)
    v4f pv4 = {0.5f, 0.5f, 0.0f, 0.0f};
    float pc = 0.5f;
    if (valid) {
        pv4 = *(const v4f*)(P + sbase + (size_t)mycell * CCH);
        pc  = P[sbase + (size_t)mycell * CCH + 4];
    }

    // (2) span obj-channel scan (L2-shared within the XCD), collect boxes
    __shared__ float4 sbox[MAXB];
    __shared__ int scnt;
    if (tid == 0) scnt = 0;
    __syncthreads();

    float myobj = 0.0f;
    int nk = (cpi + 255) >> 8;                 // 2 / 8 / 32
    for (int k0 = 0; k0 < nk; k0 += 4) {
        float o[4];
        #pragma unroll
        for (int j = 0; j < 4; ++j) {          // batch loads: 4 in flight
            int k = k0 + j;
            int cc = k * 256 + tid;
            o[j] = (k < nk && cc < cpi) ? T[sbase + (size_t)cc * CCH + 4] : 0.0f;
        }
        #pragma unroll
        for (int j = 0; j < 4; ++j) {
            int k = k0 + j;
            int cc = k * 256 + tid;
            if (k == chunk) myobj = o[j];
            if (k < nk && cc < cpi && o[j] > 0.0f) {
                int pos = atomicAdd(&scnt, 1);
                if (pos < MAXB) {
                    const float* tb = T + sbase + (size_t)cc * CCH;
                    sbox[pos] = make_float4(tb[0], tb[1], tb[2], tb[3]);
                }
            }
        }
    }
    __syncthreads();
    int n = scnt < MAXB ? scnt : MAXB;

    float acc = 0.0f;
    int lane = tid & 63, wid = tid >> 6;
    bool isobj = valid && myobj > 0.0f;

    // (3) obj-row full loss, ballot-inline (only the owning chunk computes it)
    unsigned long long mask = __ballot(isobj);
    while (mask) {
        int src = __ffsll(mask) - 1;
        mask &= mask - 1;
        int cell2 = __shfl(mycell, src, 64);
        int a2 = cell2 % 3;
        int w2 = (cell2 / 3) % g;
        int h2 = cell2 / (3 * g);
        size_t base2 = sbase + (size_t)cell2 * CCH;

        float pv = P[base2 + lane];
        float tv = T[base2 + lane];
        bool has2 = lane < (CCH - 64);          // lanes 0..20 -> ch 64..84
        float pvB = 1.0f, tvB = 1.0f;
        if (has2) { pvB = P[base2 + 64 + lane]; tvB = T[base2 + 64 + lane]; }

        float tx = __shfl(tv, 0, 64), ty = __shfl(tv, 1, 64);
        float tw = __shfl(tv, 2, 64), th = __shfl(tv, 3, 64);
        float qx = __shfl(pv, 0, 64), qy = __shfl(pv, 1, 64);
        float qw = __shfl(pv, 2, 64), qh = __shfl(pv, 3, 64);

        if (lane >= 5)   // cls ch 5..63
            acc += -(tv * __logf(pv) + (1.0f - tv) * __logf(1.0f - pv));
        if (has2)        // cls ch 64..84
            acc += -(tvB * __logf(pvB) + (1.0f - tvB) * __logf(1.0f - pvB));

        if (lane == 0) {
            float scale = 2.0f - tw * th;
            float gf = (float)g;
            float rtx = tx * gf - (float)w2;
            float rty = ty * gf - (float)h2;
            float ax = anc_x(l, a2), ay = anc_y(l, a2);
            float rtw = __logf(tw * 416.0f / ax);   // tw,th > 0 at obj cells
            float rth = __logf(th * 416.0f / ay);
            acc += (-(rtx * __logf(qx) + (1.0f - rtx) * __logf(1.0f - qx))) * scale;
            acc += (-(rty * __logf(qy) + (1.0f - rty) * __logf(1.0f - qy))) * scale;
            acc += 0.5f * (qw - rtw) * (qw - rtw) * scale;
            acc += 0.5f * (qh - rth) * (qh - rth) * scale;
        }
    }

    // (4) conf loss per cell (pred in regs, boxes in LDS)
    if (valid) {
        if (isobj) {
            acc += -__logf(pc);                    // (obj+(1-obj)*ignore)==1
        } else {
            int a = mycell % 3;
            int w = (mycell / 3) % g;
            int h = mycell / (3 * g);
            float ax = anc_x(l, a), ay = anc_y(l, a);
            float gf = (float)g;
            float pxn = (pv4.x + (float)w) / gf;
            float pyn = (pv4.y + (float)h) / gf;
            float pwn = __expf(pv4.z) * ax * (1.0f / 416.0f);
            float phn = __expf(pv4.w) * ay * (1.0f / 416.0f);
            float pl = pxn - pwn * 0.5f, pr = pxn + pwn * 0.5f;
            float pt = pyn - phn * 0.5f, pb = pyn + phn * 0.5f;
            float p_area = pwn * phn;
            float maxiou = 0.0f;
            #pragma unroll 4
            for (int k = 0; k < n; ++k) {
                float4 tb = sbox[k];
                float il = fmaxf(pl, tb.x - tb.z * 0.5f);
                float ir = fminf(pr, tb.x + tb.z * 0.5f);
                float it = fmaxf(pt, tb.y - tb.w * 0.5f);
                float ib = fminf(pb, tb.y + tb.w * 0.5f);
                float iw = fmaxf(ir - il, 0.0f);
                float ih = fmaxf(ib - it, 0.0f);
                float inter = iw * ih;
                float iou = __fdividef(inter, p_area + tb.z * tb.w - inter);
                maxiou = fmaxf(maxiou, iou);
            }
            if (maxiou < 0.5f) acc += -__logf(1.0f - pc);
        }
    }

    acc *= (1.0f / 16.0f);   // mean over batch == sum/16

    for (int off = 32; off > 0; off >>= 1)
        acc += __shfl_down(acc, off, 64);
    __shared__ float s[4];
    if (lane == 0) s[wid] = acc;
    __syncthreads();
    if (tid == 0)
        atomicAdd(out, s[0] + s[1] + s[2] + s[3]);
}

extern "C" void kernel_launch(void* const* d_in, const int* in_sizes, int n_in,
                              void* d_out, int out_size, void* d_ws, size_t ws_size,
                              hipStream_t stream) {
    const float* p0 = (const float*)d_in[0];
    const float* t0 = (const float*)d_in[1];
    const float* p1 = (const float*)d_in[2];
    const float* t1 = (const float*)d_in[3];
    const float* p2 = (const float*)d_in[4];
    const float* t2 = (const float*)d_in[5];
    float* outp = (float*)d_out;

    (void)hipMemsetAsync(d_out, 0, sizeof(float), stream);
    yolo_swz<<<672, 256, 0, stream>>>(p0, t0, p1, t1, p2, t2, outp);
}

// Round 15
// 32.269 us; speedup vs baseline: 1.3321x; 1.2613x over previous
//
#include <hip/hip_runtime.h>

#define CCH  85
#define MAXB 32

typedef float v4f __attribute__((ext_vector_type(4), aligned(4)));

// anchors fixed by reference setup_inputs; l0->mask[6,7,8], l1->[3,4,5], l2->[0,1,2]
__device__ __forceinline__ float anc_x(int l, int a) {
    if (l == 0) return (a == 0) ? 116.f : (a == 1) ? 156.f : 373.f;
    if (l == 1) return (a == 0) ?  30.f : (a == 1) ?  62.f :  59.f;
    return          (a == 0) ?  10.f : (a == 1) ?  16.f :  33.f;
}
__device__ __forceinline__ float anc_y(int l, int a) {
    if (l == 0) return (a == 0) ?  90.f : (a == 1) ? 198.f : 326.f;
    if (l == 1) return (a == 0) ?  61.f : (a == 1) ?  45.f : 119.f;
    return          (a == 0) ?  13.f : (a == 1) ?  30.f :  23.f;
}

// ---------------------------------------------------------------------------
// ONE kernel, 1024-thread blocks, XCD-pinned spans, zero cross-block comm.
// cls = bid&7 (XCD on MI355X). Per class (22 slots, l=2 first):
//   idx 0..7  : l2, b=cls,   chunk=idx      (8 chunks x 1024 cover 8112)
//   idx 8..15 : l2, b=cls+8, chunk=idx-8
//   idx 16..17: l1, b=cls,   chunk=idx-16   (2 chunks cover 2028)
//   idx 18..19: l1, b=cls+8, chunk=idx-18
//   idx 20    : l0, b=cls    (507 cells, 1 chunk)
//   idx 21    : l0, b=cls+8
// Each block re-scans its span's obj channel (redundancy 8/2/1 blocks/span,
// 4x fewer L2 requests than R14's 256-thread version); same-span blocks share
// one XCD L2 so HBM fetches each span's obj sectors once (R14-verified).
// Ref's top_k(32)+(vals>0) mask == set of obj>0 boxes (<=20/image < 32);
// set-max IoU is order-independent -> append order irrelevant.
// ---------------------------------------------------------------------------
__global__ void __launch_bounds__(1024) yolo_swz2(
        const float* __restrict__ p0, const float* __restrict__ t0,
        const float* __restrict__ p1, const float* __restrict__ t1,
        const float* __restrict__ p2, const float* __restrict__ t2,
        float* __restrict__ out) {
    int bid = blockIdx.x;
    int tid = threadIdx.x;
    int cls = bid & 7;
    int idx = bid >> 3;      // 0..21

    int l, b, chunk;
    if (idx < 8)       { l = 2; b = cls;     chunk = idx; }
    else if (idx < 16) { l = 2; b = cls + 8; chunk = idx - 8; }
    else if (idx < 18) { l = 1; b = cls;     chunk = idx - 16; }
    else if (idx < 20) { l = 1; b = cls + 8; chunk = idx - 18; }
    else if (idx < 21) { l = 0; b = cls;     chunk = 0; }
    else               { l = 0; b = cls + 8; chunk = 0; }

    int g   = (l == 0) ? 13 : (l == 1) ? 26 : 52;
    int cpi = g * g * 3;                       // 507 / 2028 / 8112
    const float* P = (l == 0) ? p0 : (l == 1) ? p1 : p2;
    const float* T = (l == 0) ? t0 : (l == 1) ? t1 : t2;
    size_t sbase = (size_t)b * cpi * CCH;

    int mycell = chunk * 1024 + tid;
    bool valid = mycell < cpi;

    // (1) own-cell pred gather first (HBM latency shadow under the scan)
    v4f pv4 = {0.5f, 0.5f, 0.0f, 0.0f};
    float pc = 0.5f;
    if (valid) {
        pv4 = *(const v4f*)(P + sbase + (size_t)mycell * CCH);
        pc  = P[sbase + (size_t)mycell * CCH + 4];
    }

    // (2) span obj scan: ALL <=8 loads issued back-to-back (8-deep MLP)
    int nk = (cpi + 1023) >> 10;               // 1 / 2 / 8
    float o[8];
    #pragma unroll
    for (int k = 0; k < 8; ++k) {
        int cc = (k << 10) + tid;
        o[k] = (k < nk && cc < cpi) ? T[sbase + (size_t)cc * CCH + 4] : 0.0f;
    }

    __shared__ float4 sbox[MAXB];
    __shared__ int scnt;
    if (tid == 0) scnt = 0;
    __syncthreads();

    float myobj = o[chunk];                    // cc==mycell when k==chunk
    #pragma unroll
    for (int k = 0; k < 8; ++k) {
        int cc = (k << 10) + tid;
        if (k < nk && cc < cpi && o[k] > 0.0f) {
            int pos = atomicAdd(&scnt, 1);
            if (pos < MAXB) {
                const float* tb = T + sbase + (size_t)cc * CCH;
                sbox[pos] = make_float4(tb[0], tb[1], tb[2], tb[3]);
            }
        }
    }
    __syncthreads();
    int n = scnt < MAXB ? scnt : MAXB;

    float acc = 0.0f;
    int lane = tid & 63, wid = tid >> 6;
    bool isobj = valid && myobj > 0.0f;

    // (3) obj-row full loss, ballot-inline per wave
    unsigned long long mask = __ballot(isobj);
    while (mask) {
        int src = __ffsll(mask) - 1;
        mask &= mask - 1;
        int cell2 = __shfl(mycell, src, 64);
        int a2 = cell2 % 3;
        int w2 = (cell2 / 3) % g;
        int h2 = cell2 / (3 * g);
        size_t base2 = sbase + (size_t)cell2 * CCH;

        float pv = P[base2 + lane];
        float tv = T[base2 + lane];
        bool has2 = lane < (CCH - 64);          // lanes 0..20 -> ch 64..84
        float pvB = 1.0f, tvB = 1.0f;
        if (has2) { pvB = P[base2 + 64 + lane]; tvB = T[base2 + 64 + lane]; }

        float tx = __shfl(tv, 0, 64), ty = __shfl(tv, 1, 64);
        float tw = __shfl(tv, 2, 64), th = __shfl(tv, 3, 64);
        float qx = __shfl(pv, 0, 64), qy = __shfl(pv, 1, 64);
        float qw = __shfl(pv, 2, 64), qh = __shfl(pv, 3, 64);

        if (lane >= 5)   // cls ch 5..63
            acc += -(tv * __logf(pv) + (1.0f - tv) * __logf(1.0f - pv));
        if (has2)        // cls ch 64..84
            acc += -(tvB * __logf(pvB) + (1.0f - tvB) * __logf(1.0f - pvB));

        if (lane == 0) {
            float scale = 2.0f - tw * th;
            float gf = (float)g;
            float rtx = tx * gf - (float)w2;
            float rty = ty * gf - (float)h2;
            float ax = anc_x(l, a2), ay = anc_y(l, a2);
            float rtw = __logf(tw * 416.0f / ax);   // tw,th > 0 at obj cells
            float rth = __logf(th * 416.0f / ay);
            acc += (-(rtx * __logf(qx) + (1.0f - rtx) * __logf(1.0f - qx))) * scale;
            acc += (-(rty * __logf(qy) + (1.0f - rty) * __logf(1.0f - qy))) * scale;
            acc += 0.5f * (qw - rtw) * (qw - rtw) * scale;
            acc += 0.5f * (qh - rth) * (qh - rth) * scale;
        }
    }

    // (4) conf loss per cell (pred in regs, boxes in LDS)
    if (valid) {
        if (isobj) {
            acc += -__logf(pc);                    // (obj+(1-obj)*ignore)==1
        } else {
            int a = mycell % 3;
            int w = (mycell / 3) % g;
            int h = mycell / (3 * g);
            float ax = anc_x(l, a), ay = anc_y(l, a);
            float gf = (float)g;
            float pxn = (pv4.x + (float)w) / gf;
            float pyn = (pv4.y + (float)h) / gf;
            float pwn = __expf(pv4.z) * ax * (1.0f / 416.0f);
            float phn = __expf(pv4.w) * ay * (1.0f / 416.0f);
            float pl = pxn - pwn * 0.5f, pr = pxn + pwn * 0.5f;
            float pt = pyn - phn * 0.5f, pb = pyn + phn * 0.5f;
            float p_area = pwn * phn;
            float maxiou = 0.0f;
            #pragma unroll 4
            for (int k = 0; k < n; ++k) {
                float4 tb = sbox[k];
                float il = fmaxf(pl, tb.x - tb.z * 0.5f);
                float ir = fminf(pr, tb.x + tb.z * 0.5f);
                float it = fmaxf(pt, tb.y - tb.w * 0.5f);
                float ib = fminf(pb, tb.y + tb.w * 0.5f);
                float iw = fmaxf(ir - il, 0.0f);
                float ih = fmaxf(ib - it, 0.0f);
                float inter = iw * ih;
                float iou = __fdividef(inter, p_area + tb.z * tb.w - inter);
                maxiou = fmaxf(maxiou, iou);
            }
            if (maxiou < 0.5f) acc += -__logf(1.0f - pc);
        }
    }

    acc *= (1.0f / 16.0f);   // mean over batch == sum/16

    for (int off = 32; off > 0; off >>= 1)
        acc += __shfl_down(acc, off, 64);
    __shared__ float s[16];
    if (lane == 0) s[wid] = acc;
    __syncthreads();
    if (tid == 0) {
        float t = 0.0f;
        #pragma unroll
        for (int k = 0; k < 16; ++k) t += s[k];
        atomicAdd(out, t);
    }
}

extern "C" void kernel_launch(void* const* d_in, const int* in_sizes, int n_in,
                              void* d_out, int out_size, void* d_ws, size_t ws_size,
                              hipStream_t stream) {
    const float* p0 = (const float*)d_in[0];
    const float* t0 = (const float*)d_in[1];
    const float* p1 = (const float*)d_in[2];
    const float* t1 = (const float*)d_in[3];
    const float* p2 = (const float*)d_in[4];
    const float* t2 = (const float*)d_in[5];
    float* outp = (float*)d_out;

    (void)hipMemsetAsync(d_out, 0, sizeof(float), stream);
    yolo_swz2<<<176, 1024, 0, stream>>>(p0, t0, p1, t1, p2, t2, outp);
}